// Round 6
// baseline (63.857 us; speedup 1.0000x reference)
//
#include <hip/hip_runtime.h>

#define NN 62
#define FF 5
#define KC 4
#define CO 64
#define NSEL 31
#define NF 310
#define NBATCH 4096
#define TPB 256        // 4 waves
#define BPB 8          // batches per block (4 waves x 2 each)
#define XS_ST 32       // xs row stride in bf16 elems (20 used, rest zero; A-frag reads k=0..31)
#define AD_ST 72       // adj row stride in bf16 elems
#define UT_BY 144      // U_t row (per col) stride bytes (72 j-elems; odd 16B-slot stride)
#define XS_BY 64       // xs row stride bytes
#define AD_BY 144      // adj row stride bytes
#define WT_BY 80       // Wt row stride bytes (40 bf16)

typedef __bf16 bf16x8 __attribute__((ext_vector_type(8)));
typedef float f32x4 __attribute__((ext_vector_type(4)));

#define MFMA(A, B, C) __builtin_amdgcn_mfma_f32_16x16x32_bf16((A), (B), (C), 0, 0, 0)

__device__ __forceinline__ unsigned short f2bf(float f) {
    unsigned u = __float_as_uint(f);
    u += 0x7fffu + ((u >> 16) & 1u);
    return (unsigned short)(u >> 16);
}
__device__ __forceinline__ float bf2f(unsigned short s) {
    return __uint_as_float(((unsigned)s) << 16);
}
__device__ __forceinline__ bf16x8 ldfrag(const unsigned short* p, int byte_off) {
    return *(const bf16x8*)((const char*)p + byte_off);
}

// one-group fc-weight load into a NAMED register array (static indices after unroll)
#define LOAD_FC(dst, mt_, nt_)                                                  \
    do {                                                                        \
        _Pragma("unroll")                                                       \
        for (int ii = 0; ii < 4; ++ii) {                                        \
            int r_ = (mt_) * 16 + g * 4 + ii;                                   \
            int rr_ = (r_ < NN) ? r_ : (NN - 1);  /* clamp: keep loads in-bounds */ \
            int base_ = rr_ * CO + (nt_) * 16 + c;                              \
            const float* f1p_ = fc1_w + base_ * 3;                              \
            const float* f2p_ = fc2_w + base_ * 3;                              \
            const float* fgp_ = cls_w + base_ * 2;                              \
            dst[ii * 8 + 0] = f1p_[0]; dst[ii * 8 + 1] = f1p_[1]; dst[ii * 8 + 2] = f1p_[2]; \
            dst[ii * 8 + 3] = f2p_[0]; dst[ii * 8 + 4] = f2p_[1]; dst[ii * 8 + 5] = f2p_[2]; \
            dst[ii * 8 + 6] = fgp_[0]; dst[ii * 8 + 7] = fgp_[1];               \
        }                                                                       \
    } while (0)

// consume one (mt,nt) group: 3 W frags, 6 MFMAs, relu+bias, acc FMAs from `cur`
#define BODY_FC(cur, mt_, nt_)                                                  \
    do {                                                                        \
        bf16x8 W1f = ldfrag(s_wt, (0 * 64 + (nt_) * 16 + c) * WT_BY + g * 16);  \
        bf16x8 W2f = ldfrag(s_wt, (1 * 64 + (nt_) * 16 + c) * WT_BY + g * 16);  \
        bf16x8 Wgf = ldfrag(s_wt, (2 * 64 + (nt_) * 16 + c) * WT_BY + g * 16);  \
        const f32x4 z_ = {0.f, 0.f, 0.f, 0.f};                                  \
        f32x4 C1a = MFMA(A1f[0][mt_], W1f, z_);                                 \
        f32x4 C1b = MFMA(A1f[1][mt_], W1f, z_);                                 \
        f32x4 Cga = MFMA(A1f[0][mt_], Wgf, z_);                                 \
        f32x4 Cgb = MFMA(A1f[1][mt_], Wgf, z_);                                 \
        f32x4 C2a = MFMA(A2f[0][mt_], W2f, z_);                                 \
        f32x4 C2b = MFMA(A2f[1][mt_], W2f, z_);                                 \
        _Pragma("unroll")                                                       \
        for (int i = 0; i < 4; ++i) {                                           \
            int r = (mt_) * 16 + g * 4 + i;                                     \
            if (r < NN) {                                                       \
                float f10 = cur[i*8+0], f11 = cur[i*8+1], f12 = cur[i*8+2];     \
                float f20 = cur[i*8+3], f21 = cur[i*8+4], f22 = cur[i*8+5];     \
                float fg0 = cur[i*8+6], fg1 = cur[i*8+7];                       \
                float h1a = fmaxf(C1a[i] + b1v[nt_], 0.f);                      \
                float h1b = fmaxf(C1b[i] + b1v[nt_], 0.f);                      \
                float h2a = fmaxf(C2a[i] + b2v[nt_], 0.f);                      \
                float h2b = fmaxf(C2b[i] + b2v[nt_], 0.f);                      \
                float hga = fmaxf(Cga[i] + bgv[nt_], 0.f);                      \
                float hgb = fmaxf(Cgb[i] + bgv[nt_], 0.f);                      \
                acc[0][0] += h1a * f10; acc[0][1] += h1a * f11; acc[0][2] += h1a * f12; \
                acc[0][3] += h2a * f20; acc[0][4] += h2a * f21; acc[0][5] += h2a * f22; \
                acc[0][6] += hga * fg0; acc[0][7] += hga * fg1;                 \
                acc[1][0] += h1b * f10; acc[1][1] += h1b * f11; acc[1][2] += h1b * f12; \
                acc[1][3] += h2b * f20; acc[1][4] += h2b * f21; acc[1][5] += h2b * f22; \
                acc[1][6] += hgb * fg0; acc[1][7] += hgb * fg1;                 \
            }                                                                   \
        }                                                                       \
    } while (0)

__global__ __launch_bounds__(TPB) void gnn_mfma(
    const float* __restrict__ x, const float* __restrict__ adj,
    const int* __restrict__ mask_idx,
    const float* __restrict__ gc_w, const float* __restrict__ gc_b,
    const float* __restrict__ gc1_w, const float* __restrict__ gc1_b,
    const float* __restrict__ gc2_w, const float* __restrict__ gc2_b,
    const float* __restrict__ fc1_w, const float* __restrict__ fc1_b,
    const float* __restrict__ fc2_w, const float* __restrict__ fc2_b,
    const float* __restrict__ cls_w, const float* __restrict__ cls_b,
    float* __restrict__ out)
{
    __shared__ __align__(16) unsigned short s_adjb[64 * AD_ST];     // 9216 B
    __shared__ __align__(16) unsigned short s_wt[3 * 64 * 40];      // 15360 B
    __shared__ float s_bias[3][64];                                 // 768 B
    __shared__ float s_dis1[64];                                    // 256 B
    __shared__ float s_dis2[BPB][64];                               // 2048 B
    __shared__ float s_msk[BPB][64];                                // 2048 B
    __shared__ __align__(16) unsigned short s_ut[4][16 * AD_ST];    // 9216 B
    __shared__ __align__(16) unsigned short s_xs[4][2][64 * XS_ST]; // 32768 B
    // total 71680 B -> 2 blocks/CU guaranteed (R5's 79872 risked 1 with alloc rounding)

    const int t = threadIdx.x;
    const int w = t >> 6, lane = t & 63;
    const int g = lane >> 4, c = lane & 15;
    const int b0 = blockIdx.x * BPB;

    // ================= block-cooperative staging =================
    for (int i = t; i < 64 * AD_ST; i += TPB) {
        int r = i / AD_ST, cc = i - r * AD_ST;
        float v = (r < NN && cc < NN) ? adj[r * NN + cc] : 0.0f;
        s_adjb[i] = f2bf(v);
    }
    for (int i = t; i < 3 * 64 * 40; i += TPB) {
        int head = i / 2560, rem = i - head * 2560;
        int o = rem / 40, kf = rem - o * 40;
        const float* wp = (head == 0) ? gc1_w : (head == 1) ? gc2_w : gc_w;
        s_wt[i] = f2bf((kf < KC * FF) ? wp[kf * CO + o] : 0.0f);
    }
    if (t < 192) {
        int head = t >> 6, o = t & 63;
        const float* bp = (head == 0) ? gc1_b : (head == 1) ? gc2_b : gc_b;
        s_bias[head][o] = bp[o];
    }
    for (int i = t; i < BPB * 64; i += TPB) ((float*)s_msk)[i] = 0.0f;
    if (t < 64) {
        float d = 0.0f;
        if (t < NN)
            for (int l = 0; l < NN; ++l) d += adj[t * NN + l];   // fp32, L1-resident
        s_dis1[t] = (d > 0.0f) ? rsqrtf(d) : 0.0f;
    }
    __syncthreads();   // B1

    if (t < BPB * NSEL) {
        int bt = t / NSEL, s = t - bt * NSEL;
        s_msk[bt][mask_idx[(b0 + bt) * NSEL + s]] = 1.0f;  // same-value races benign
    }
    __syncthreads();   // B2

    for (int task = t; task < BPB * 64; task += TPB) {
        int bt = task >> 6, j = task & 63;
        float s = 0.0f;
        if (j < NN) {
            for (int l = 0; l < NN; ++l) s += adj[j * NN + l] * s_msk[bt][l];  // fp32
            s *= s_msk[bt][j];
        }
        s_dis2[bt][j] = (s > 0.0f) ? rsqrtf(s) : 0.0f;
    }
    __syncthreads();   // B3  -- last barrier; waves independent from here

    // ================= wave-private: 2 batches per wave =================
    {   // zero xs once per wave (pad cols 20..31 and rows 62,63 stay zero forever)
        unsigned* z = (unsigned*)&s_xs[w][0][0];
        for (int i = lane; i < 2048; i += 64) z[i] = 0u;
    }

    bf16x8 A1f[2][4], A2f[2][4];

    #pragma unroll
    for (int bi = 0; bi < 2; ++bi) {
        const int bb = w * 2 + bi;
        const int b  = b0 + bb;

        // ---- stage x0 (path1 = x, path2 = x*m) into xs k=0 slice ----
        const float* xb = x + (size_t)b * NF;
        for (int e = lane; e < NF; e += 64) {
            int n = e / 5, f = e - n * 5;
            float v = xb[e];
            s_xs[w][0][n * XS_ST + f] = f2bf(v);
            s_xs[w][1][n * XS_ST + f] = f2bf(v * s_msk[bb][n]);
        }

        // ---- per-lane dis selection (col<5: path1, col<10: path2, else 0) ----
        float dsel[16];
        const float* dsp = (c < 5) ? s_dis1 : s_dis2[bb];
        #pragma unroll
        for (int mt = 0; mt < 4; ++mt)
            #pragma unroll
            for (int i = 0; i < 4; ++i)
                dsel[mt * 4 + i] = (c < 10) ? dsp[mt * 16 + g * 4 + i] : 0.0f;

        // ---- x0 fragments (C-layout: row = mt*16+g*4+i, col = c) ----
        const int f_c = (c < 5) ? c : (c < 10 ? c - 5 : 0);
        const unsigned short* xsp = (c < 5) ? s_xs[w][0] : s_xs[w][1];
        f32x4 xA[4];
        #pragma unroll
        for (int mt = 0; mt < 4; ++mt)
            #pragma unroll
            for (int i = 0; i < 4; ++i) {
                int r = mt * 16 + g * 4 + i;
                xA[mt][i] = (c < 10) ? bf2f(xsp[r * XS_ST + f_c]) : 0.0f;
            }

        // ---- U0 = dis .* x0  ->  U^T LDS [col][j] ----
        #pragma unroll
        for (int mt = 0; mt < 4; ++mt) {
            unsigned p01 = (unsigned)f2bf(dsel[mt*4+0] * xA[mt][0]) |
                           ((unsigned)f2bf(dsel[mt*4+1] * xA[mt][1]) << 16);
            unsigned p23 = (unsigned)f2bf(dsel[mt*4+2] * xA[mt][2]) |
                           ((unsigned)f2bf(dsel[mt*4+3] * xA[mt][3]) << 16);
            *(uint2*)((char*)s_ut[w] + c * UT_BY + mt * 32 + g * 8) = make_uint2(p01, p23);
        }

        // ---- adj A-fragments (row = mt*16+c, k = kf2*32+g*8+i) ----
        bf16x8 adjA[4][2];
        #pragma unroll
        for (int mt = 0; mt < 4; ++mt)
            #pragma unroll
            for (int kf2 = 0; kf2 < 2; ++kf2)
                adjA[mt][kf2] = ldfrag(s_adjb, (mt * 16 + c) * AD_BY + kf2 * 64 + g * 16);

        // ---- Chebyshev steps k=1..3 (wave-private, no barriers) ----
        f32x4 x1f[4];
        #pragma unroll
        for (int k = 1; k <= 3; ++k) {
            const float cc_k = (k == 1) ? 1.0f : 2.0f;
            bf16x8 Uf0 = ldfrag(s_ut[w], c * UT_BY + 0 + g * 16);
            bf16x8 Uf1 = ldfrag(s_ut[w], c * UT_BY + 64 + g * 16);
            #pragma unroll
            for (int mt = 0; mt < 4; ++mt) {
                f32x4 Cv = {0.f, 0.f, 0.f, 0.f};
                Cv = MFMA(adjA[mt][0], Uf0, Cv);
                Cv = MFMA(adjA[mt][1], Uf1, Cv);
                f32x4 xn;
                #pragma unroll
                for (int i = 0; i < 4; ++i) {
                    float v = -cc_k * dsel[mt * 4 + i] * Cv[i];
                    if (k == 2) v -= xA[mt][i];
                    if (k == 3) v -= x1f[mt][i];
                    xn[i] = v;
                }
                if (c < 10) {
                    unsigned short* dst = (c < 5) ? s_xs[w][0] : s_xs[w][1];
                    #pragma unroll
                    for (int i = 0; i < 4; ++i) {
                        int r = mt * 16 + g * 4 + i;
                        dst[r * XS_ST + k * 5 + f_c] = f2bf(xn[i]);
                    }
                }
                if (k < 3) {
                    unsigned p01 = (unsigned)f2bf(dsel[mt*4+0] * xn[0]) |
                                   ((unsigned)f2bf(dsel[mt*4+1] * xn[1]) << 16);
                    unsigned p23 = (unsigned)f2bf(dsel[mt*4+2] * xn[2]) |
                                   ((unsigned)f2bf(dsel[mt*4+3] * xn[3]) << 16);
                    *(uint2*)((char*)s_ut[w] + c * UT_BY + mt * 32 + g * 8) = make_uint2(p01, p23);
                }
                if (k == 1) x1f[mt] = xn;
            }
        }

        // ---- einsum A-frags for this batch (row n = mt*16+c, k = kf) ----
        #pragma unroll
        for (int mt = 0; mt < 4; ++mt) {
            A1f[bi][mt] = ldfrag(s_xs[w][0], (mt * 16 + c) * XS_BY + g * 16);
            A2f[bi][mt] = ldfrag(s_xs[w][1], (mt * 16 + c) * XS_BY + g * 16);
        }
    } // bi

    // ====== fused einsum + ReLU + FC, one-group-ahead fc prefetch ======
    float acc[2][8];
    #pragma unroll
    for (int bi = 0; bi < 2; ++bi)
        #pragma unroll
        for (int q = 0; q < 8; ++q) acc[bi][q] = 0.0f;

    float b1v[4], b2v[4], bgv[4];
    #pragma unroll
    for (int nt = 0; nt < 4; ++nt) {
        b1v[nt] = s_bias[0][nt * 16 + c];
        b2v[nt] = s_bias[1][nt * 16 + c];
        bgv[nt] = s_bias[2][nt * 16 + c];
    }

    float fbA[32], fbB[32];
    LOAD_FC(fbA, 0, 0);
    #pragma unroll
    for (int j = 0; j < 16; ++j) {
        const int mt = j >> 2, nt = j & 3;
        if ((j & 1) == 0) {
            if (j < 15) { const int jn = j + 1; LOAD_FC(fbB, (jn >> 2), (jn & 3)); }
            BODY_FC(fbA, mt, nt);
        } else {
            if (j < 15) { const int jn = j + 1; LOAD_FC(fbA, (jn >> 2), (jn & 3)); }
            BODY_FC(fbB, mt, nt);
        }
    }

    // ---- wave reduction ----
    #pragma unroll
    for (int off = 32; off > 0; off >>= 1)
        #pragma unroll
        for (int bi = 0; bi < 2; ++bi)
            #pragma unroll
            for (int q = 0; q < 8; ++q)
                acc[bi][q] += __shfl_down(acc[bi][q], off);

    if (lane == 0) {
        #pragma unroll
        for (int bi = 0; bi < 2; ++bi) {
            const int b = b0 + w * 2 + bi;
            float l0 = acc[bi][0] + fc1_b[0];
            float l1 = acc[bi][1] + fc1_b[1];
            float l2 = acc[bi][2] + fc1_b[2];
            float m0 = acc[bi][3] + fc2_b[0];
            float m1 = acc[bi][4] + fc2_b[1];
            float m2 = acc[bi][5] + fc2_b[2];
            float g0 = acc[bi][6] + cls_b[0];
            float g1 = acc[bi][7] + cls_b[1];
            float mx = fmaxf(g0, g1);
            float e0 = expf(g0 - mx), e1 = expf(g1 - mx);
            float inv = 1.0f / (e0 + e1);
            float p0 = e0 * inv, p1 = e1 * inv;
            out[b * 3 + 0] = l0 * p0 + m0 * p1;
            out[b * 3 + 1] = l1 * p0 + m1 * p1;
            out[b * 3 + 2] = l2 * p0 + m2 * p1;
        }
    }
}

extern "C" void kernel_launch(void* const* d_in, const int* in_sizes, int n_in,
                              void* d_out, int out_size, void* d_ws, size_t ws_size,
                              hipStream_t stream) {
    const float* x      = (const float*)d_in[0];
    const float* adj    = (const float*)d_in[1];
    const int*   midx   = (const int*)  d_in[2];
    const float* gc_w   = (const float*)d_in[3];
    const float* gc_b   = (const float*)d_in[4];
    const float* gc1_w  = (const float*)d_in[5];
    const float* gc1_b  = (const float*)d_in[6];
    const float* gc2_w  = (const float*)d_in[7];
    const float* gc2_b  = (const float*)d_in[8];
    const float* fc1_w  = (const float*)d_in[9];
    const float* fc1_b  = (const float*)d_in[10];
    const float* fc2_w  = (const float*)d_in[11];
    const float* fc2_b  = (const float*)d_in[12];
    const float* cls_w  = (const float*)d_in[13];
    const float* cls_b  = (const float*)d_in[14];
    float* o = (float*)d_out;
    hipLaunchKernelGGL(gnn_mfma, dim3(NBATCH / BPB), dim3(TPB), 0, stream,
        x, adj, midx, gc_w, gc_b, gc1_w, gc1_b, gc2_w, gc2_b,
        fc1_w, fc1_b, fc2_w, fc2_b, cls_w, cls_b, o);
}

// Round 7
// 51.821 us; speedup vs baseline: 1.2323x; 1.2323x over previous
//
#include <hip/hip_runtime.h>

#define NN 62
#define FF 5
#define KC 4
#define CO 64
#define NSEL 31
#define NF 310
#define NBATCH 4096
#define TPB 256        // 4 waves
#define BPB 16         // batches per block (4 waves x 4 each, 2 pairs)
#define XS_ST 32       // xs row stride in bf16 elems (20 used, rest zero)
#define AD_ST 72       // adj row stride in bf16 elems
#define UT_BY 144      // U_t row (per col) stride bytes
#define XS_BY 64       // xs row stride bytes
#define AD_BY 144      // adj row stride bytes
#define WT_BY 80       // Wt row stride bytes (40 bf16)

typedef __bf16 bf16x8 __attribute__((ext_vector_type(8)));
typedef float f32x4 __attribute__((ext_vector_type(4)));
typedef unsigned short u16x8 __attribute__((ext_vector_type(8)));

#define MFMA(A, B, C) __builtin_amdgcn_mfma_f32_16x16x32_bf16((A), (B), (C), 0, 0, 0)

__device__ __forceinline__ unsigned short f2bf(float f) {
    unsigned u = __float_as_uint(f);
    u += 0x7fffu + ((u >> 16) & 1u);
    return (unsigned short)(u >> 16);
}
__device__ __forceinline__ float bf2f(unsigned short s) {
    return __uint_as_float(((unsigned)s) << 16);
}
__device__ __forceinline__ bf16x8 ldfrag(const unsigned short* p, int byte_off) {
    return *(const bf16x8*)((const char*)p + byte_off);
}

__global__ __launch_bounds__(TPB) void gnn_mfma(
    const float* __restrict__ x, const float* __restrict__ adj,
    const int* __restrict__ mask_idx,
    const float* __restrict__ gc_w, const float* __restrict__ gc_b,
    const float* __restrict__ gc1_w, const float* __restrict__ gc1_b,
    const float* __restrict__ gc2_w, const float* __restrict__ gc2_b,
    const float* __restrict__ fc1_w, const float* __restrict__ fc1_b,
    const float* __restrict__ fc2_w, const float* __restrict__ fc2_b,
    const float* __restrict__ cls_w, const float* __restrict__ cls_b,
    float* __restrict__ out)
{
    __shared__ __align__(16) unsigned short s_adjb[64 * AD_ST];     // 9216 B
    __shared__ __align__(16) unsigned short s_wt[3 * 64 * 40];      // 15360 B
    __shared__ __align__(16) unsigned short s_fc[NN * CO * 8];      // 63488 B: {fc1x3,fc2x3,clsx2} bf16
    __shared__ float s_bias[3][64];                                 // 768 B
    __shared__ float s_dis1[64];                                    // 256 B
    __shared__ float s_dis2[BPB][64];                               // 4096 B
    __shared__ float s_msk[BPB][64];                                // 4096 B
    __shared__ __align__(16) unsigned short s_ut[4][16 * AD_ST];    // 9216 B
    __shared__ __align__(16) unsigned short s_xs[4][2][64 * XS_ST]; // 32768 B
    // total 139264 B -> 1 block/CU; fc traffic from L2 drops ~30x vs per-lane global loads

    const int t = threadIdx.x;
    const int w = t >> 6, lane = t & 63;
    const int g = lane >> 4, c = lane & 15;
    const int b0 = blockIdx.x * BPB;

    // ================= block-cooperative staging =================
    for (int i = t; i < 64 * AD_ST; i += TPB) {
        int r = i / AD_ST, cc = i - r * AD_ST;
        float v = (r < NN && cc < NN) ? adj[r * NN + cc] : 0.0f;
        s_adjb[i] = f2bf(v);
    }
    for (int i = t; i < 3 * 64 * 40; i += TPB) {
        int head = i / 2560, rem = i - head * 2560;
        int o = rem / 40, kf = rem - o * 40;
        const float* wp = (head == 0) ? gc1_w : (head == 1) ? gc2_w : gc_w;
        s_wt[i] = f2bf((kf < KC * FF) ? wp[kf * CO + o] : 0.0f);
    }
    // fused fc table: coalesced global reads, one ds_write_b128 per idx
    for (int i = t; i < NN * CO; i += TPB) {
        const float* f1p = fc1_w + i * 3;
        const float* f2p = fc2_w + i * 3;
        const float* fgp = cls_w + i * 2;
        u16x8 v;
        v[0] = f2bf(f1p[0]); v[1] = f2bf(f1p[1]); v[2] = f2bf(f1p[2]);
        v[3] = f2bf(f2p[0]); v[4] = f2bf(f2p[1]); v[5] = f2bf(f2p[2]);
        v[6] = f2bf(fgp[0]); v[7] = f2bf(fgp[1]);
        *(u16x8*)&s_fc[i * 8] = v;
    }
    if (t < 192) {
        int head = t >> 6, o = t & 63;
        const float* bp = (head == 0) ? gc1_b : (head == 1) ? gc2_b : gc_b;
        s_bias[head][o] = bp[o];
    }
    for (int i = t; i < BPB * 64; i += TPB) ((float*)s_msk)[i] = 0.0f;
    if (t < 64) {
        float d = 0.0f;
        if (t < NN)
            for (int l = 0; l < NN; ++l) d += adj[t * NN + l];   // fp32, L1-resident
        s_dis1[t] = (d > 0.0f) ? rsqrtf(d) : 0.0f;
    }
    __syncthreads();   // B1

    for (int i = t; i < BPB * NSEL; i += TPB) {
        int bt = i / NSEL, s = i - bt * NSEL;
        s_msk[bt][mask_idx[(b0 + bt) * NSEL + s]] = 1.0f;  // same-value races benign
    }
    __syncthreads();   // B2

    for (int task = t; task < BPB * 64; task += TPB) {
        int bt = task >> 6, j = task & 63;
        float s = 0.0f;
        if (j < NN) {
            for (int l = 0; l < NN; ++l) s += adj[j * NN + l] * s_msk[bt][l];  // fp32
            s *= s_msk[bt][j];
        }
        s_dis2[bt][j] = (s > 0.0f) ? rsqrtf(s) : 0.0f;
    }
    __syncthreads();   // B3  -- last barrier; waves independent from here

    // ================= wave-private: 4 batches per wave (2 pairs) =================
    {   // zero xs once per wave (pad cols 20..31 and rows 62,63 stay zero forever)
        unsigned* z = (unsigned*)&s_xs[w][0][0];
        for (int i = lane; i < 2048; i += 64) z[i] = 0u;
    }

    float b1v[4], b2v[4], bgv[4];
    #pragma unroll
    for (int nt = 0; nt < 4; ++nt) {
        b1v[nt] = s_bias[0][nt * 16 + c];
        b2v[nt] = s_bias[1][nt * 16 + c];
        bgv[nt] = s_bias[2][nt * 16 + c];
    }

    // adj A-fragments (batch-independent): row = mt*16+c, k = kf2*32+g*8+i
    bf16x8 adjA[4][2];
    #pragma unroll
    for (int mt = 0; mt < 4; ++mt)
        #pragma unroll
        for (int kf2 = 0; kf2 < 2; ++kf2)
            adjA[mt][kf2] = ldfrag(s_adjb, (mt * 16 + c) * AD_BY + kf2 * 64 + g * 16);

    for (int p = 0; p < 2; ++p) {
        const int bbase = w * 4 + p * 2;
        bf16x8 A1f[2][4], A2f[2][4];

        #pragma unroll
        for (int bi = 0; bi < 2; ++bi) {
            const int bb = bbase + bi;
            const int b  = b0 + bb;

            // ---- stage x0 (path1 = x, path2 = x*m) into xs k=0 slice ----
            const float* xb = x + (size_t)b * NF;
            for (int e = lane; e < NF; e += 64) {
                int n = e / 5, f = e - n * 5;
                float v = xb[e];
                s_xs[w][0][n * XS_ST + f] = f2bf(v);
                s_xs[w][1][n * XS_ST + f] = f2bf(v * s_msk[bb][n]);
            }

            // ---- per-lane dis selection (col<5: path1, col<10: path2, else 0) ----
            float dsel[16];
            const float* dsp = (c < 5) ? s_dis1 : s_dis2[bb];
            #pragma unroll
            for (int mt = 0; mt < 4; ++mt)
                #pragma unroll
                for (int i = 0; i < 4; ++i)
                    dsel[mt * 4 + i] = (c < 10) ? dsp[mt * 16 + g * 4 + i] : 0.0f;

            // ---- x0 fragments (C-layout: row = mt*16+g*4+i, col = c) ----
            const int f_c = (c < 5) ? c : (c < 10 ? c - 5 : 0);
            const unsigned short* xsp = (c < 5) ? s_xs[w][0] : s_xs[w][1];
            f32x4 xA[4];
            #pragma unroll
            for (int mt = 0; mt < 4; ++mt)
                #pragma unroll
                for (int i = 0; i < 4; ++i) {
                    int r = mt * 16 + g * 4 + i;
                    xA[mt][i] = (c < 10) ? bf2f(xsp[r * XS_ST + f_c]) : 0.0f;
                }

            // ---- U0 = dis .* x0  ->  U^T LDS [col][j] ----
            #pragma unroll
            for (int mt = 0; mt < 4; ++mt) {
                unsigned p01 = (unsigned)f2bf(dsel[mt*4+0] * xA[mt][0]) |
                               ((unsigned)f2bf(dsel[mt*4+1] * xA[mt][1]) << 16);
                unsigned p23 = (unsigned)f2bf(dsel[mt*4+2] * xA[mt][2]) |
                               ((unsigned)f2bf(dsel[mt*4+3] * xA[mt][3]) << 16);
                *(uint2*)((char*)s_ut[w] + c * UT_BY + mt * 32 + g * 8) = make_uint2(p01, p23);
            }

            // ---- Chebyshev steps k=1..3 (wave-private, no barriers) ----
            f32x4 x1f[4];
            #pragma unroll
            for (int k = 1; k <= 3; ++k) {
                const float cc_k = (k == 1) ? 1.0f : 2.0f;
                bf16x8 Uf0 = ldfrag(s_ut[w], c * UT_BY + 0 + g * 16);
                bf16x8 Uf1 = ldfrag(s_ut[w], c * UT_BY + 64 + g * 16);
                #pragma unroll
                for (int mt = 0; mt < 4; ++mt) {
                    f32x4 Cv = {0.f, 0.f, 0.f, 0.f};
                    Cv = MFMA(adjA[mt][0], Uf0, Cv);
                    Cv = MFMA(adjA[mt][1], Uf1, Cv);
                    f32x4 xn;
                    #pragma unroll
                    for (int i = 0; i < 4; ++i) {
                        float v = -cc_k * dsel[mt * 4 + i] * Cv[i];
                        if (k == 2) v -= xA[mt][i];
                        if (k == 3) v -= x1f[mt][i];
                        xn[i] = v;
                    }
                    if (c < 10) {
                        unsigned short* dst = (c < 5) ? s_xs[w][0] : s_xs[w][1];
                        #pragma unroll
                        for (int i = 0; i < 4; ++i) {
                            int r = mt * 16 + g * 4 + i;
                            dst[r * XS_ST + k * 5 + f_c] = f2bf(xn[i]);
                        }
                    }
                    if (k < 3) {
                        unsigned p01 = (unsigned)f2bf(dsel[mt*4+0] * xn[0]) |
                                       ((unsigned)f2bf(dsel[mt*4+1] * xn[1]) << 16);
                        unsigned p23 = (unsigned)f2bf(dsel[mt*4+2] * xn[2]) |
                                       ((unsigned)f2bf(dsel[mt*4+3] * xn[3]) << 16);
                        *(uint2*)((char*)s_ut[w] + c * UT_BY + mt * 32 + g * 8) = make_uint2(p01, p23);
                    }
                    if (k == 1) x1f[mt] = xn;
                }
            }

            // ---- einsum A-frags for this batch (row n = mt*16+c, k = kf) ----
            #pragma unroll
            for (int mt = 0; mt < 4; ++mt) {
                A1f[bi][mt] = ldfrag(s_xs[w][0], (mt * 16 + c) * XS_BY + g * 16);
                A2f[bi][mt] = ldfrag(s_xs[w][1], (mt * 16 + c) * XS_BY + g * 16);
            }
        } // bi

        // ====== fused einsum + ReLU + FC (fc weights from LDS) ======
        float acc[2][8];
        #pragma unroll
        for (int bi = 0; bi < 2; ++bi)
            #pragma unroll
            for (int q = 0; q < 8; ++q) acc[bi][q] = 0.0f;

        #pragma unroll
        for (int mt = 0; mt < 4; ++mt) {
            #pragma unroll
            for (int nt = 0; nt < 4; ++nt) {
                bf16x8 W1f = ldfrag(s_wt, (0 * 64 + nt * 16 + c) * WT_BY + g * 16);
                bf16x8 W2f = ldfrag(s_wt, (1 * 64 + nt * 16 + c) * WT_BY + g * 16);
                bf16x8 Wgf = ldfrag(s_wt, (2 * 64 + nt * 16 + c) * WT_BY + g * 16);
                const f32x4 z = {0.f, 0.f, 0.f, 0.f};
                f32x4 C1a = MFMA(A1f[0][mt], W1f, z);
                f32x4 C1b = MFMA(A1f[1][mt], W1f, z);
                f32x4 Cga = MFMA(A1f[0][mt], Wgf, z);
                f32x4 Cgb = MFMA(A1f[1][mt], Wgf, z);
                f32x4 C2a = MFMA(A2f[0][mt], W2f, z);
                f32x4 C2b = MFMA(A2f[1][mt], W2f, z);
                #pragma unroll
                for (int i = 0; i < 4; ++i) {
                    int r = mt * 16 + g * 4 + i;
                    if (r < NN) {
                        const u16x8 fcv = *(const u16x8*)((const char*)s_fc +
                                            (((r * CO + nt * 16 + c)) << 4));
                        float f10 = bf2f(fcv[0]), f11 = bf2f(fcv[1]), f12 = bf2f(fcv[2]);
                        float f20 = bf2f(fcv[3]), f21 = bf2f(fcv[4]), f22 = bf2f(fcv[5]);
                        float fg0 = bf2f(fcv[6]), fg1 = bf2f(fcv[7]);
                        float h1a = fmaxf(C1a[i] + b1v[nt], 0.f);
                        float h1b = fmaxf(C1b[i] + b1v[nt], 0.f);
                        float h2a = fmaxf(C2a[i] + b2v[nt], 0.f);
                        float h2b = fmaxf(C2b[i] + b2v[nt], 0.f);
                        float hga = fmaxf(Cga[i] + bgv[nt], 0.f);
                        float hgb = fmaxf(Cgb[i] + bgv[nt], 0.f);
                        acc[0][0] += h1a * f10; acc[0][1] += h1a * f11; acc[0][2] += h1a * f12;
                        acc[0][3] += h2a * f20; acc[0][4] += h2a * f21; acc[0][5] += h2a * f22;
                        acc[0][6] += hga * fg0; acc[0][7] += hga * fg1;
                        acc[1][0] += h1b * f10; acc[1][1] += h1b * f11; acc[1][2] += h1b * f12;
                        acc[1][3] += h2b * f20; acc[1][4] += h2b * f21; acc[1][5] += h2b * f22;
                        acc[1][6] += hgb * fg0; acc[1][7] += hgb * fg1;
                    }
                }
            }
        }

        // ---- wave reduction + per-pair output ----
        #pragma unroll
        for (int off = 32; off > 0; off >>= 1)
            #pragma unroll
            for (int bi = 0; bi < 2; ++bi)
                #pragma unroll
                for (int q = 0; q < 8; ++q)
                    acc[bi][q] += __shfl_down(acc[bi][q], off);

        if (lane == 0) {
            #pragma unroll
            for (int bi = 0; bi < 2; ++bi) {
                const int b = b0 + bbase + bi;
                float l0 = acc[bi][0] + fc1_b[0];
                float l1 = acc[bi][1] + fc1_b[1];
                float l2 = acc[bi][2] + fc1_b[2];
                float m0 = acc[bi][3] + fc2_b[0];
                float m1 = acc[bi][4] + fc2_b[1];
                float m2 = acc[bi][5] + fc2_b[2];
                float g0 = acc[bi][6] + cls_b[0];
                float g1 = acc[bi][7] + cls_b[1];
                float mx = fmaxf(g0, g1);
                float e0 = expf(g0 - mx), e1 = expf(g1 - mx);
                float inv = 1.0f / (e0 + e1);
                float p0 = e0 * inv, p1 = e1 * inv;
                out[b * 3 + 0] = l0 * p0 + m0 * p1;
                out[b * 3 + 1] = l1 * p0 + m1 * p1;
                out[b * 3 + 2] = l2 * p0 + m2 * p1;
            }
        }
    } // pair
}

extern "C" void kernel_launch(void* const* d_in, const int* in_sizes, int n_in,
                              void* d_out, int out_size, void* d_ws, size_t ws_size,
                              hipStream_t stream) {
    const float* x      = (const float*)d_in[0];
    const float* adj    = (const float*)d_in[1];
    const int*   midx   = (const int*)  d_in[2];
    const float* gc_w   = (const float*)d_in[3];
    const float* gc_b   = (const float*)d_in[4];
    const float* gc1_w  = (const float*)d_in[5];
    const float* gc1_b  = (const float*)d_in[6];
    const float* gc2_w  = (const float*)d_in[7];
    const float* gc2_b  = (const float*)d_in[8];
    const float* fc1_w  = (const float*)d_in[9];
    const float* fc1_b  = (const float*)d_in[10];
    const float* fc2_w  = (const float*)d_in[11];
    const float* fc2_b  = (const float*)d_in[12];
    const float* cls_w  = (const float*)d_in[13];
    const float* cls_b  = (const float*)d_in[14];
    float* o = (float*)d_out;
    hipLaunchKernelGGL(gnn_mfma, dim3(NBATCH / BPB), dim3(TPB), 0, stream,
        x, adj, midx, gc_w, gc_b, gc1_w, gc1_b, gc2_w, gc2_b,
        fc1_w, fc1_b, fc2_w, fc2_b, cls_w, cls_b, o);
}

// Round 8
// 43.300 us; speedup vs baseline: 1.4748x; 1.1968x over previous
//
#include <hip/hip_runtime.h>

#define NN 62
#define FF 5
#define KC 4
#define CO 64
#define NSEL 31
#define NF 310
#define NBATCH 4096
#define TPB 512        // 8 waves -> 2 waves/SIMD in ONE block (multi-block residency never materialized R5-R7)
#define BPB 16         // 8 waves x 2 batches (1 pair per wave)
#define XS_ST 32       // xs row stride in bf16 (kf 0..19 real, 20..23 zero, bytes 48..63 = U^T chunk slots)
#define AD_ST 72
#define XS_BY 64
#define AD_BY 144
#define WT_BY 80

typedef __bf16 bf16x8 __attribute__((ext_vector_type(8)));
typedef float f32x4 __attribute__((ext_vector_type(4)));
typedef unsigned short u16x8 __attribute__((ext_vector_type(8)));

#define MFMA(A, B, C) __builtin_amdgcn_mfma_f32_16x16x32_bf16((A), (B), (C), 0, 0, 0)

static __device__ __forceinline__ unsigned short f2bf(float f) {
    unsigned u = __float_as_uint(f);
    u += 0x7fffu + ((u >> 16) & 1u);
    return (unsigned short)(u >> 16);
}
static __device__ __forceinline__ float bf2f(unsigned short s) {
    return __uint_as_float(((unsigned)s) << 16);
}
static __device__ __forceinline__ bf16x8 ldfrag(const unsigned short* p, int byte_off) {
    return *(const bf16x8*)((const char*)p + byte_off);
}
static __device__ __forceinline__ unsigned pack2(float a, float b) {
    return (unsigned)f2bf(a) | ((unsigned)f2bf(b) << 16);
}

__global__ __launch_bounds__(TPB) void gnn_mfma(
    const float* __restrict__ x, const float* __restrict__ adj,
    const int* __restrict__ mask_idx,
    const float* __restrict__ gc_w, const float* __restrict__ gc_b,
    const float* __restrict__ gc1_w, const float* __restrict__ gc1_b,
    const float* __restrict__ gc2_w, const float* __restrict__ gc2_b,
    const float* __restrict__ fc1_w, const float* __restrict__ fc1_b,
    const float* __restrict__ fc2_w, const float* __restrict__ fc2_b,
    const float* __restrict__ cls_w, const float* __restrict__ cls_b,
    float* __restrict__ out)
{
    __shared__ __align__(16) unsigned short s_adjb[64 * AD_ST];     // 9216 B
    __shared__ __align__(16) unsigned short s_wt[3 * 64 * 40];      // 15360 B (kf 20..39 zero)
    __shared__ __align__(16) unsigned short s_fc[NN * CO * 8];      // 63488 B {fc1x3,fc2x3,clsx2}
    __shared__ float s_bias[3][64];                                 // 768 B
    __shared__ float s_dis1[64];                                    // 256 B
    __shared__ float s_dis2[BPB][64];                               // 4096 B
    __shared__ unsigned s_mb[BPB][2];                               // 128 B bitmask
    __shared__ __align__(16) unsigned short s_xs[8][2][64 * XS_ST]; // 65536 B per-wave
    // total 158848 B <= 163840 -> one 8-wave block/CU

    const int t = threadIdx.x;
    const int w = t >> 6, lane = t & 63;
    const int g = lane >> 4, c = lane & 15;
    const int b0 = blockIdx.x * BPB;

    // ================= block-cooperative staging =================
    for (int i = t; i < 64 * AD_ST; i += TPB) {
        int r = i / AD_ST, cc = i - r * AD_ST;
        float v = (r < NN && cc < NN) ? adj[r * NN + cc] : 0.0f;
        s_adjb[i] = f2bf(v);
    }
    for (int i = t; i < 3 * 64 * 40; i += TPB) {
        int head = i / 2560, rem = i - head * 2560;
        int o = rem / 40, kf = rem - o * 40;
        const float* wp = (head == 0) ? gc1_w : (head == 1) ? gc2_w : gc_w;
        s_wt[i] = f2bf((kf < KC * FF) ? wp[kf * CO + o] : 0.0f);
    }
    for (int i = t; i < NN * CO; i += TPB) {
        const float* f1p = fc1_w + i * 3;
        const float* f2p = fc2_w + i * 3;
        const float* fgp = cls_w + i * 2;
        u16x8 v;
        v[0] = f2bf(f1p[0]); v[1] = f2bf(f1p[1]); v[2] = f2bf(f1p[2]);
        v[3] = f2bf(f2p[0]); v[4] = f2bf(f2p[1]); v[5] = f2bf(f2p[2]);
        v[6] = f2bf(fgp[0]); v[7] = f2bf(fgp[1]);
        *(u16x8*)&s_fc[i * 8] = v;
    }
    if (t < 192) {
        int head = t >> 6, o = t & 63;
        const float* bp = (head == 0) ? gc1_b : (head == 1) ? gc2_b : gc_b;
        s_bias[head][o] = bp[o];
    }
    if (t < BPB * 2) ((unsigned*)s_mb)[t] = 0u;
    if (t < 64) {
        float d = 0.0f;
        if (t < NN)
            for (int l = 0; l < NN; ++l) d += adj[t * NN + l];
        s_dis1[t] = (d > 0.0f) ? rsqrtf(d) : 0.0f;
    }
    __syncthreads();   // B1

    for (int i = t; i < BPB * NSEL; i += TPB) {
        int bt = i / NSEL, s = i - bt * NSEL;
        int idx = mask_idx[(b0 + bt) * NSEL + s];
        atomicOr(&s_mb[bt][idx >> 5], 1u << (idx & 31));
    }
    __syncthreads();   // B2

    for (int task = t; task < BPB * 64; task += TPB) {
        int bt = task >> 6, j = task & 63;
        float s = 0.0f;
        if (j < NN) {
            unsigned mlo = s_mb[bt][0], mhi = s_mb[bt][1];
            for (int l = 0; l < NN; ++l) {
                unsigned bit = (l < 32) ? ((mlo >> l) & 1u) : ((mhi >> (l - 32)) & 1u);
                s += bit ? adj[j * NN + l] : 0.0f;
            }
            unsigned bj = (j < 32) ? ((mlo >> j) & 1u) : ((mhi >> (j - 32)) & 1u);
            s = bj ? s : 0.0f;
        }
        s_dis2[bt][j] = (s > 0.0f) ? rsqrtf(s) : 0.0f;
    }
    __syncthreads();   // B3  -- last barrier; waves independent from here

    // ================= wave-private: 1 pair (2 batches) per wave =================
    {   // zero this wave's xs (pads + rows 62/63 + U slots start finite)
        unsigned* z = (unsigned*)&s_xs[w][0][0];
        for (int i = lane; i < 2048; i += 64) z[i] = 0u;
    }

    float b1v[4], b2v[4], bgv[4];
    #pragma unroll
    for (int nt = 0; nt < 4; ++nt) {
        b1v[nt] = s_bias[0][nt * 16 + c];
        b2v[nt] = s_bias[1][nt * 16 + c];
        bgv[nt] = s_bias[2][nt * 16 + c];
    }

    // adj A-fragments (batch-independent)
    bf16x8 adjA[4][2];
    #pragma unroll
    for (int mt = 0; mt < 4; ++mt)
        #pragma unroll
        for (int kf2 = 0; kf2 < 2; ++kf2)
            adjA[mt][kf2] = ldfrag(s_adjb, (mt * 16 + c) * AD_BY + kf2 * 64 + g * 16);

    // U^T read addressing (slots live at bytes 48..63 of xs rows 0..39)
    const unsigned short* xsU = (c >= 5 && c < 10) ? s_xs[w][1] : s_xs[w][0];
    const int c5r = (c < 5) ? c : (c < 10) ? (c - 5) : ((c < 15) ? (c - 10) : 4);
    const int f_c = (c < 5) ? c : (c < 10 ? c - 5 : 0);

    bf16x8 A1f[2][4], A2f[2][4];

    #pragma unroll
    for (int bi = 0; bi < 2; ++bi) {
        const int bb = w * 2 + bi;
        const int b  = b0 + bb;

        // ---- stage x0 (path1 = x, path2 = x*m) into xs k=0 slice ----
        const float* xb = x + (size_t)b * NF;
        const unsigned mlo = s_mb[bb][0], mhi = s_mb[bb][1];
        for (int e = lane; e < NF; e += 64) {
            int n = e / 5, f = e - n * 5;
            float v = xb[e];
            unsigned bit = (n < 32) ? ((mlo >> n) & 1u) : ((mhi >> (n - 32)) & 1u);
            s_xs[w][0][n * XS_ST + f] = f2bf(v);
            s_xs[w][1][n * XS_ST + f] = f2bf(bit ? v : 0.0f);
        }

        // ---- per-lane dis selection ----
        float dsel[16];
        const float* dsp = (c < 5) ? s_dis1 : s_dis2[bb];
        #pragma unroll
        for (int mt = 0; mt < 4; ++mt)
            #pragma unroll
            for (int i = 0; i < 4; ++i)
                dsel[mt * 4 + i] = (c < 10) ? dsp[mt * 16 + g * 4 + i] : 0.0f;

        // ---- x0 fragments (C-layout: row = mt*16+g*4+i, col = c) ----
        const unsigned short* xsp = (c >= 5 && c < 10) ? s_xs[w][1] : s_xs[w][0];
        f32x4 xA[4];
        #pragma unroll
        for (int mt = 0; mt < 4; ++mt)
            #pragma unroll
            for (int i = 0; i < 4; ++i) {
                int r = mt * 16 + g * 4 + i;
                xA[mt][i] = (c < 10) ? bf2f(xsp[r * XS_ST + f_c]) : 0.0f;
            }

        // ---- U0 chunks into xs pad slots: chunk(j)=j>>3 at row f_c*8+chunk, byte 48+(j&7)*2 ----
        if (c < 10) {
            unsigned short* xsW = (c < 5) ? s_xs[w][0] : s_xs[w][1];
            #pragma unroll
            for (int mt = 0; mt < 4; ++mt) {
                unsigned p01 = pack2(dsel[mt*4+0] * xA[mt][0], dsel[mt*4+1] * xA[mt][1]);
                unsigned p23 = pack2(dsel[mt*4+2] * xA[mt][2], dsel[mt*4+3] * xA[mt][3]);
                int byte = (f_c * 8 + 2 * mt + (g >> 1)) * 64 + 48 + (g & 1) * 8;
                *(uint2*)((char*)xsW + byte) = make_uint2(p01, p23);
            }
        }

        // ---- Chebyshev steps k=1..3 (wave-private) ----
        f32x4 x1f[4];
        #pragma unroll
        for (int k = 1; k <= 3; ++k) {
            const float cck = (k == 1) ? 1.0f : 2.0f;
            bf16x8 Uf0 = ldfrag(xsU, (c5r * 8 + g) * 64 + 48);
            bf16x8 Uf1 = ldfrag(xsU, (c5r * 8 + 4 + g) * 64 + 48);
            #pragma unroll
            for (int mt = 0; mt < 4; ++mt) {
                f32x4 Cv = {0.f, 0.f, 0.f, 0.f};
                Cv = MFMA(adjA[mt][0], Uf0, Cv);
                Cv = MFMA(adjA[mt][1], Uf1, Cv);
                f32x4 xn;
                #pragma unroll
                for (int i = 0; i < 4; ++i) {
                    float v = -cck * dsel[mt * 4 + i] * Cv[i];
                    if (k == 2) v -= xA[mt][i];
                    if (k == 3) v -= x1f[mt][i];
                    xn[i] = v;
                }
                if (c < 10) {
                    unsigned short* dst = (c < 5) ? s_xs[w][0] : s_xs[w][1];
                    #pragma unroll
                    for (int i = 0; i < 4; ++i)
                        dst[(mt * 16 + g * 4 + i) * XS_ST + k * 5 + f_c] = f2bf(xn[i]);
                    if (k < 3) {
                        unsigned p01 = pack2(dsel[mt*4+0] * xn[0], dsel[mt*4+1] * xn[1]);
                        unsigned p23 = pack2(dsel[mt*4+2] * xn[2], dsel[mt*4+3] * xn[3]);
                        int byte = (f_c * 8 + 2 * mt + (g >> 1)) * 64 + 48 + (g & 1) * 8;
                        *(uint2*)((char*)dst + byte) = make_uint2(p01, p23);
                    }
                }
                if (k == 1) x1f[mt] = xn;
            }
        }

        // ---- einsum A-frags for this batch ----
        #pragma unroll
        for (int mt = 0; mt < 4; ++mt) {
            A1f[bi][mt] = ldfrag(s_xs[w][0], (mt * 16 + c) * XS_BY + g * 16);
            A2f[bi][mt] = ldfrag(s_xs[w][1], (mt * 16 + c) * XS_BY + g * 16);
        }
    } // bi

    // ====== fused einsum + ReLU + FC (nt-outer: 12 W-frag reads total) ======
    float acc[2][8];
    #pragma unroll
    for (int bi = 0; bi < 2; ++bi)
        #pragma unroll
        for (int q = 0; q < 8; ++q) acc[bi][q] = 0.0f;

    #pragma unroll
    for (int nt = 0; nt < 4; ++nt) {
        bf16x8 W1f = ldfrag(s_wt, (0 * 64 + nt * 16 + c) * WT_BY + g * 16);
        bf16x8 W2f = ldfrag(s_wt, (1 * 64 + nt * 16 + c) * WT_BY + g * 16);
        bf16x8 Wgf = ldfrag(s_wt, (2 * 64 + nt * 16 + c) * WT_BY + g * 16);
        #pragma unroll
        for (int mt = 0; mt < 4; ++mt) {
            const f32x4 z = {0.f, 0.f, 0.f, 0.f};
            f32x4 C1a = MFMA(A1f[0][mt], W1f, z);
            f32x4 C1b = MFMA(A1f[1][mt], W1f, z);
            f32x4 Cga = MFMA(A1f[0][mt], Wgf, z);
            f32x4 Cgb = MFMA(A1f[1][mt], Wgf, z);
            f32x4 C2a = MFMA(A2f[0][mt], W2f, z);
            f32x4 C2b = MFMA(A2f[1][mt], W2f, z);
            #pragma unroll
            for (int i = 0; i < 4; ++i) {
                int r = mt * 16 + g * 4 + i;
                if (r < NN) {
                    const u16x8 fcv = *(const u16x8*)((const char*)s_fc +
                                        ((r * CO + nt * 16 + c) << 4));
                    float f10 = bf2f(fcv[0]), f11 = bf2f(fcv[1]), f12 = bf2f(fcv[2]);
                    float f20 = bf2f(fcv[3]), f21 = bf2f(fcv[4]), f22 = bf2f(fcv[5]);
                    float fg0 = bf2f(fcv[6]), fg1 = bf2f(fcv[7]);
                    float h1a = fmaxf(C1a[i] + b1v[nt], 0.f);
                    float h1b = fmaxf(C1b[i] + b1v[nt], 0.f);
                    float h2a = fmaxf(C2a[i] + b2v[nt], 0.f);
                    float h2b = fmaxf(C2b[i] + b2v[nt], 0.f);
                    float hga = fmaxf(Cga[i] + bgv[nt], 0.f);
                    float hgb = fmaxf(Cgb[i] + bgv[nt], 0.f);
                    acc[0][0] += h1a * f10; acc[0][1] += h1a * f11; acc[0][2] += h1a * f12;
                    acc[0][3] += h2a * f20; acc[0][4] += h2a * f21; acc[0][5] += h2a * f22;
                    acc[0][6] += hga * fg0; acc[0][7] += hga * fg1;
                    acc[1][0] += h1b * f10; acc[1][1] += h1b * f11; acc[1][2] += h1b * f12;
                    acc[1][3] += h2b * f20; acc[1][4] += h2b * f21; acc[1][5] += h2b * f22;
                    acc[1][6] += hgb * fg0; acc[1][7] += hgb * fg1;
                }
            }
        }
    }

    // ---- wave reduction + output ----
    #pragma unroll
    for (int off = 32; off > 0; off >>= 1)
        #pragma unroll
        for (int bi = 0; bi < 2; ++bi)
            #pragma unroll
            for (int q = 0; q < 8; ++q)
                acc[bi][q] += __shfl_down(acc[bi][q], off);

    if (lane == 0) {
        #pragma unroll
        for (int bi = 0; bi < 2; ++bi) {
            const int b = b0 + w * 2 + bi;
            float l0 = acc[bi][0] + fc1_b[0];
            float l1 = acc[bi][1] + fc1_b[1];
            float l2 = acc[bi][2] + fc1_b[2];
            float m0 = acc[bi][3] + fc2_b[0];
            float m1 = acc[bi][4] + fc2_b[1];
            float m2 = acc[bi][5] + fc2_b[2];
            float g0 = acc[bi][6] + cls_b[0];
            float g1 = acc[bi][7] + cls_b[1];
            float mx = fmaxf(g0, g1);
            float e0 = expf(g0 - mx), e1 = expf(g1 - mx);
            float inv = 1.0f / (e0 + e1);
            float p0 = e0 * inv, p1 = e1 * inv;
            out[b * 3 + 0] = l0 * p0 + m0 * p1;
            out[b * 3 + 1] = l1 * p0 + m1 * p1;
            out[b * 3 + 2] = l2 * p0 + m2 * p1;
        }
    }
}

extern "C" void kernel_launch(void* const* d_in, const int* in_sizes, int n_in,
                              void* d_out, int out_size, void* d_ws, size_t ws_size,
                              hipStream_t stream) {
    const float* x      = (const float*)d_in[0];
    const float* adj    = (const float*)d_in[1];
    const int*   midx   = (const int*)  d_in[2];
    const float* gc_w   = (const float*)d_in[3];
    const float* gc_b   = (const float*)d_in[4];
    const float* gc1_w  = (const float*)d_in[5];
    const float* gc1_b  = (const float*)d_in[6];
    const float* gc2_w  = (const float*)d_in[7];
    const float* gc2_b  = (const float*)d_in[8];
    const float* fc1_w  = (const float*)d_in[9];
    const float* fc1_b  = (const float*)d_in[10];
    const float* fc2_w  = (const float*)d_in[11];
    const float* fc2_b  = (const float*)d_in[12];
    const float* cls_w  = (const float*)d_in[13];
    const float* cls_b  = (const float*)d_in[14];
    float* o = (float*)d_out;
    hipLaunchKernelGGL(gnn_mfma, dim3(NBATCH / BPB), dim3(TPB), 0, stream,
        x, adj, midx, gc_w, gc_b, gc1_w, gc1_b, gc2_w, gc2_b,
        fc1_w, fc1_b, fc2_w, fc2_b, cls_w, cls_b, o);
}

// Round 9
// 30.376 us; speedup vs baseline: 2.1022x; 1.4255x over previous
//
#include <hip/hip_runtime.h>

#define NN 62
#define FF 5
#define KC 4
#define CO 64
#define NSEL 31
#define NF 310
#define NBATCH 4096
#define TPB 512        // 8 waves, 2/SIMD, one block/CU
#define BPB 16         // 8 waves x 2 batches
#define XS_ST 24       // xs row stride elems (kf 0..19 real, 20..23 zero; g=3 frag reads spill into next row: finite garbage x zero-W)
#define XS_BY 48
#define AD_ST 72
#define AD_BY 144
#define WT_BY 80
#define U_BY  144      // U^T row stride bytes (72 bf16) -> (c+g)&7 uniform bank slots

typedef __bf16 bf16x8 __attribute__((ext_vector_type(8)));
typedef __bf16 bf16x4 __attribute__((ext_vector_type(4)));
typedef float f32x4 __attribute__((ext_vector_type(4)));
typedef unsigned short u16x8 __attribute__((ext_vector_type(8)));

#define MFMA(A, B, C) __builtin_amdgcn_mfma_f32_16x16x32_bf16((A), (B), (C), 0, 0, 0)

static __device__ __forceinline__ unsigned short f2bf(float f) {  // native: compiler emits v_cvt_pk_bf16_f32
    __bf16 b = (__bf16)f;
    return __builtin_bit_cast(unsigned short, b);
}
static __device__ __forceinline__ float bf2f(unsigned short s) {
    return __uint_as_float(((unsigned)s) << 16);
}
static __device__ __forceinline__ bf16x8 ldfrag(const unsigned short* p, int byte_off) {
    return *(const bf16x8*)((const char*)p + byte_off);
}

__global__ __launch_bounds__(TPB) void gnn_mfma(
    const float* __restrict__ x, const float* __restrict__ adj,
    const int* __restrict__ mask_idx,
    const float* __restrict__ gc_w, const float* __restrict__ gc_b,
    const float* __restrict__ gc1_w, const float* __restrict__ gc1_b,
    const float* __restrict__ gc2_w, const float* __restrict__ gc2_b,
    const float* __restrict__ fc1_w, const float* __restrict__ fc1_b,
    const float* __restrict__ fc2_w, const float* __restrict__ fc2_b,
    const float* __restrict__ cls_w, const float* __restrict__ cls_b,
    float* __restrict__ out)
{
    __shared__ __align__(16) unsigned short s_adjb[64 * AD_ST];      // 9216 B
    __shared__ __align__(16) unsigned short s_wt[3 * 64 * 40];       // 15360 B (kf>=20 zero)
    __shared__ __align__(16) unsigned short s_fc[NN * CO * 8];       // 63488 B {fc1x3,fc2x3,clsx2}
    __shared__ float s_bias[3][64];                                  // 768 B
    __shared__ float s_dis1[64];                                     // 256 B
    __shared__ float s_dis2[BPB][64];                                // 4096 B
    __shared__ unsigned s_mb[BPB][2];                                // 128 B
    __shared__ __align__(16) unsigned short s_ut[8][16 * AD_ST];     // 18432 B per-wave U^T
    __shared__ __align__(16) unsigned short s_xs[8 * 2 * 64 * XS_ST + 8]; // 49168 B (+16B tail pad)
    // total 160912 B <= 163840

    const int t = threadIdx.x;
    const int w = t >> 6, lane = t & 63;
    const int g = lane >> 4, c = lane & 15;
    const int b0 = blockIdx.x * BPB;

    // ================= block-cooperative staging =================
    for (int i = t; i < 64 * AD_ST; i += TPB) {
        int r = i / AD_ST, cc = i - r * AD_ST;
        float v = (r < NN && cc < NN) ? adj[r * NN + cc] : 0.0f;
        s_adjb[i] = f2bf(v);
    }
    for (int i = t; i < 3 * 64 * 40; i += TPB) {
        int head = i / 2560, rem = i - head * 2560;
        int o = rem / 40, kf = rem - o * 40;
        const float* wp = (head == 0) ? gc1_w : (head == 1) ? gc2_w : gc_w;
        s_wt[i] = f2bf((kf < KC * FF) ? wp[kf * CO + o] : 0.0f);
    }
    for (int i = t; i < NN * CO; i += TPB) {
        const float* f1p = fc1_w + i * 3;
        const float* f2p = fc2_w + i * 3;
        const float* fgp = cls_w + i * 2;
        u16x8 v;
        v[0] = f2bf(f1p[0]); v[1] = f2bf(f1p[1]); v[2] = f2bf(f1p[2]);
        v[3] = f2bf(f2p[0]); v[4] = f2bf(f2p[1]); v[5] = f2bf(f2p[2]);
        v[6] = f2bf(fgp[0]); v[7] = f2bf(fgp[1]);
        *(u16x8*)&s_fc[i * 8] = v;
    }
    if (t < 192) {
        int head = t >> 6, o = t & 63;
        const float* bp = (head == 0) ? gc1_b : (head == 1) ? gc2_b : gc_b;
        s_bias[head][o] = bp[o];
    }
    if (t < BPB * 2) ((unsigned*)s_mb)[t] = 0u;
    if (t < 8) s_xs[8 * 2 * 64 * XS_ST + t] = 0;   // tail pad (read by g=3 frag of last row)
    __syncthreads();   // B1

    for (int i = t; i < BPB * NSEL; i += TPB) {
        int bt = i / NSEL, s = i - bt * NSEL;
        int idx = mask_idx[(b0 + bt) * NSEL + s];
        atomicOr(&s_mb[bt][idx >> 5], 1u << (idx & 31));
    }
    __syncthreads();   // B2

    // ---- dis1/dis2 via MFMA on staged bf16 adj (waves 0..4) ----
    if (w < 4) {
        unsigned mlo = s_mb[c][0], mhi = s_mb[c][1];
        bf16x8 M0, M1;
        #pragma unroll
        for (int e = 0; e < 8; ++e) {
            int l = g * 8 + e;
            M0[e] = __builtin_bit_cast(__bf16, (unsigned short)(((mlo >> l) & 1u) ? 0x3F80 : 0));
            M1[e] = __builtin_bit_cast(__bf16, (unsigned short)(((mhi >> l) & 1u) ? 0x3F80 : 0));
        }
        bf16x8 A0 = ldfrag(s_adjb, (w * 16 + c) * AD_BY + g * 16);
        bf16x8 A1 = ldfrag(s_adjb, (w * 16 + c) * AD_BY + 64 + g * 16);
        f32x4 Cd = {0.f, 0.f, 0.f, 0.f};
        Cd = MFMA(A0, M0, Cd);
        Cd = MFMA(A1, M1, Cd);
        #pragma unroll
        for (int i = 0; i < 4; ++i) {
            int j = w * 16 + g * 4 + i;
            unsigned bit = (j < 32) ? ((mlo >> j) & 1u) : ((mhi >> (j - 32)) & 1u);
            float s = bit ? Cd[i] : 0.0f;
            s_dis2[c][j] = (s > 0.0f) ? rsqrtf(s) : 0.0f;
        }
    } else if (w == 4) {
        bf16x8 ones;
        #pragma unroll
        for (int e = 0; e < 8; ++e)
            ones[e] = __builtin_bit_cast(__bf16, (unsigned short)0x3F80);
        #pragma unroll
        for (int mt = 0; mt < 4; ++mt) {
            bf16x8 A0 = ldfrag(s_adjb, (mt * 16 + c) * AD_BY + g * 16);
            bf16x8 A1 = ldfrag(s_adjb, (mt * 16 + c) * AD_BY + 64 + g * 16);
            f32x4 Cd = {0.f, 0.f, 0.f, 0.f};
            Cd = MFMA(A0, ones, Cd);
            Cd = MFMA(A1, ones, Cd);
            if (c == 0) {
                #pragma unroll
                for (int i = 0; i < 4; ++i) {
                    float d = Cd[i];
                    s_dis1[mt * 16 + g * 4 + i] = (d > 0.0f) ? rsqrtf(d) : 0.0f;
                }
            }
        }
    }
    __syncthreads();   // B3 -- last barrier; waves independent from here

    // ================= wave-private: 1 pair (2 batches) per wave =================
    unsigned short* xsW0 = &s_xs[(w * 2 + 0) * 64 * XS_ST];
    unsigned short* xsW1 = &s_xs[(w * 2 + 1) * 64 * XS_ST];
    unsigned short* utW  = &s_ut[w][0];
    {   // zero xs (both paths) + U buffer once
        unsigned* z = (unsigned*)xsW0;
        for (int i = lane; i < 64 * XS_ST; i += 64) z[i] = 0u;   // 2 paths contiguous: 2*64*24/2 u32
        unsigned* zu = (unsigned*)utW;
        for (int i = lane; i < 16 * AD_ST / 2; i += 64) zu[i] = 0u;
    }

    float b1v[4], b2v[4], bgv[4];
    #pragma unroll
    for (int nt = 0; nt < 4; ++nt) {
        b1v[nt] = s_bias[0][nt * 16 + c];
        b2v[nt] = s_bias[1][nt * 16 + c];
        bgv[nt] = s_bias[2][nt * 16 + c];
    }

    bf16x8 adjA[4][2];
    #pragma unroll
    for (int mt = 0; mt < 4; ++mt)
        #pragma unroll
        for (int kf2 = 0; kf2 < 2; ++kf2)
            adjA[mt][kf2] = ldfrag(s_adjb, (mt * 16 + c) * AD_BY + kf2 * 64 + g * 16);

    const int f_c = (c < 5) ? c : (c < 10 ? c - 5 : 0);
    bf16x8 A1f[2][4], A2f[2][4];

    #pragma unroll
    for (int bi = 0; bi < 2; ++bi) {
        const int bb = w * 2 + bi;
        const int b  = b0 + bb;

        // ---- stage x0 (path1 = x, path2 = x*m) ----
        const float* xb = x + (size_t)b * NF;
        const unsigned mlo = s_mb[bb][0], mhi = s_mb[bb][1];
        for (int e = lane; e < NF; e += 64) {
            int n = e / 5, f = e - n * 5;
            float v = xb[e];
            unsigned bit = (n < 32) ? ((mlo >> n) & 1u) : ((mhi >> (n - 32)) & 1u);
            xsW0[n * XS_ST + f] = f2bf(v);
            xsW1[n * XS_ST + f] = f2bf(bit ? v : 0.0f);
        }

        // ---- per-lane dis selection ----
        float dsel[16];
        const float* dsp = (c < 5) ? s_dis1 : s_dis2[bb];
        #pragma unroll
        for (int mt = 0; mt < 4; ++mt)
            #pragma unroll
            for (int i = 0; i < 4; ++i)
                dsel[mt * 4 + i] = (c < 10) ? dsp[mt * 16 + g * 4 + i] : 0.0f;

        // ---- x0 fragments (C-layout: row = mt*16+g*4+i, col = c) ----
        const unsigned short* xsp = (c >= 5 && c < 10) ? xsW1 : xsW0;
        f32x4 xA[4];
        #pragma unroll
        for (int mt = 0; mt < 4; ++mt)
            #pragma unroll
            for (int i = 0; i < 4; ++i) {
                int r = mt * 16 + g * 4 + i;
                xA[mt][i] = (c < 10) ? bf2f(xsp[r * XS_ST + f_c]) : 0.0f;
            }

        // ---- U0 = dis .* x0 -> U^T[q=c][j], one b64 write per mt ----
        if (c < 10) {
            #pragma unroll
            for (int mt = 0; mt < 4; ++mt) {
                bf16x4 uv;
                uv[0] = (__bf16)(dsel[mt*4+0] * xA[mt][0]);
                uv[1] = (__bf16)(dsel[mt*4+1] * xA[mt][1]);
                uv[2] = (__bf16)(dsel[mt*4+2] * xA[mt][2]);
                uv[3] = (__bf16)(dsel[mt*4+3] * xA[mt][3]);
                *(bf16x4*)((char*)utW + c * U_BY + (mt * 16 + g * 4) * 2) = uv;
            }
        }

        // ---- Chebyshev k=1..3 (wave-private) ----
        f32x4 x1f[4];
        #pragma unroll
        for (int k = 1; k <= 3; ++k) {
            const float cck = (k == 1) ? 1.0f : 2.0f;
            bf16x8 Uf0 = ldfrag(utW, c * U_BY + g * 16);
            bf16x8 Uf1 = ldfrag(utW, c * U_BY + 64 + g * 16);
            #pragma unroll
            for (int mt = 0; mt < 4; ++mt) {
                f32x4 Cv = {0.f, 0.f, 0.f, 0.f};
                Cv = MFMA(adjA[mt][0], Uf0, Cv);
                Cv = MFMA(adjA[mt][1], Uf1, Cv);
                f32x4 xn;
                #pragma unroll
                for (int i = 0; i < 4; ++i) {
                    float v = -cck * dsel[mt * 4 + i] * Cv[i];
                    if (k == 2) v -= xA[mt][i];
                    if (k == 3) v -= x1f[mt][i];
                    xn[i] = v;
                }
                if (c < 10) {
                    unsigned short* dst = (c < 5) ? xsW0 : xsW1;
                    #pragma unroll
                    for (int i = 0; i < 4; ++i)
                        dst[(mt * 16 + g * 4 + i) * XS_ST + k * 5 + f_c] = f2bf(xn[i]);
                    if (k < 3) {
                        bf16x4 uv;
                        uv[0] = (__bf16)(dsel[mt*4+0] * xn[0]);
                        uv[1] = (__bf16)(dsel[mt*4+1] * xn[1]);
                        uv[2] = (__bf16)(dsel[mt*4+2] * xn[2]);
                        uv[3] = (__bf16)(dsel[mt*4+3] * xn[3]);
                        *(bf16x4*)((char*)utW + c * U_BY + (mt * 16 + g * 4) * 2) = uv;
                    }
                }
                if (k == 1) x1f[mt] = xn;
            }
        }

        // ---- einsum A-frags (row n = mt*16+c, k = kf; kf>=20 junk x zero-W) ----
        #pragma unroll
        for (int mt = 0; mt < 4; ++mt) {
            A1f[bi][mt] = ldfrag(xsW0, (mt * 16 + c) * XS_BY + g * 16);
            A2f[bi][mt] = ldfrag(xsW1, (mt * 16 + c) * XS_BY + g * 16);
        }
    } // bi

    // ====== fused einsum + ReLU + FC (fc weights from LDS) ======
    float acc[2][8];
    #pragma unroll
    for (int bi = 0; bi < 2; ++bi)
        #pragma unroll
        for (int q = 0; q < 8; ++q) acc[bi][q] = 0.0f;

    #pragma unroll
    for (int nt = 0; nt < 4; ++nt) {
        bf16x8 W1f = ldfrag(s_wt, (0 * 64 + nt * 16 + c) * WT_BY + g * 16);
        bf16x8 W2f = ldfrag(s_wt, (1 * 64 + nt * 16 + c) * WT_BY + g * 16);
        bf16x8 Wgf = ldfrag(s_wt, (2 * 64 + nt * 16 + c) * WT_BY + g * 16);
        #pragma unroll
        for (int mt = 0; mt < 4; ++mt) {
            const f32x4 z = {0.f, 0.f, 0.f, 0.f};
            f32x4 C1a = MFMA(A1f[0][mt], W1f, z);
            f32x4 C1b = MFMA(A1f[1][mt], W1f, z);
            f32x4 Cga = MFMA(A1f[0][mt], Wgf, z);
            f32x4 Cgb = MFMA(A1f[1][mt], Wgf, z);
            f32x4 C2a = MFMA(A2f[0][mt], W2f, z);
            f32x4 C2b = MFMA(A2f[1][mt], W2f, z);
            #pragma unroll
            for (int i = 0; i < 4; ++i) {
                int r = mt * 16 + g * 4 + i;
                if (r < NN) {
                    const u16x8 fcv = *(const u16x8*)((const char*)s_fc +
                                        ((r * CO + nt * 16 + c) << 4));
                    float f10 = bf2f(fcv[0]), f11 = bf2f(fcv[1]), f12 = bf2f(fcv[2]);
                    float f20 = bf2f(fcv[3]), f21 = bf2f(fcv[4]), f22 = bf2f(fcv[5]);
                    float fg0 = bf2f(fcv[6]), fg1 = bf2f(fcv[7]);
                    float h1a = fmaxf(C1a[i] + b1v[nt], 0.f);
                    float h1b = fmaxf(C1b[i] + b1v[nt], 0.f);
                    float h2a = fmaxf(C2a[i] + b2v[nt], 0.f);
                    float h2b = fmaxf(C2b[i] + b2v[nt], 0.f);
                    float hga = fmaxf(Cga[i] + bgv[nt], 0.f);
                    float hgb = fmaxf(Cgb[i] + bgv[nt], 0.f);
                    acc[0][0] += h1a * f10; acc[0][1] += h1a * f11; acc[0][2] += h1a * f12;
                    acc[0][3] += h2a * f20; acc[0][4] += h2a * f21; acc[0][5] += h2a * f22;
                    acc[0][6] += hga * fg0; acc[0][7] += hga * fg1;
                    acc[1][0] += h1b * f10; acc[1][1] += h1b * f11; acc[1][2] += h1b * f12;
                    acc[1][3] += h2b * f20; acc[1][4] += h2b * f21; acc[1][5] += h2b * f22;
                    acc[1][6] += hgb * fg0; acc[1][7] += hgb * fg1;
                }
            }
        }
    }

    // ---- wave reduction + output ----
    #pragma unroll
    for (int off = 32; off > 0; off >>= 1)
        #pragma unroll
        for (int bi = 0; bi < 2; ++bi)
            #pragma unroll
            for (int q = 0; q < 8; ++q)
                acc[bi][q] += __shfl_down(acc[bi][q], off);

    if (lane == 0) {
        #pragma unroll
        for (int bi = 0; bi < 2; ++bi) {
            const int b = b0 + w * 2 + bi;
            float l0 = acc[bi][0] + fc1_b[0];
            float l1 = acc[bi][1] + fc1_b[1];
            float l2 = acc[bi][2] + fc1_b[2];
            float m0 = acc[bi][3] + fc2_b[0];
            float m1 = acc[bi][4] + fc2_b[1];
            float m2 = acc[bi][5] + fc2_b[2];
            float g0 = acc[bi][6] + cls_b[0];
            float g1 = acc[bi][7] + cls_b[1];
            float mx = fmaxf(g0, g1);
            float e0 = expf(g0 - mx), e1 = expf(g1 - mx);
            float inv = 1.0f / (e0 + e1);
            float p0 = e0 * inv, p1 = e1 * inv;
            out[b * 3 + 0] = l0 * p0 + m0 * p1;
            out[b * 3 + 1] = l1 * p0 + m1 * p1;
            out[b * 3 + 2] = l2 * p0 + m2 * p1;
        }
    }
}

extern "C" void kernel_launch(void* const* d_in, const int* in_sizes, int n_in,
                              void* d_out, int out_size, void* d_ws, size_t ws_size,
                              hipStream_t stream) {
    const float* x      = (const float*)d_in[0];
    const float* adj    = (const float*)d_in[1];
    const int*   midx   = (const int*)  d_in[2];
    const float* gc_w   = (const float*)d_in[3];
    const float* gc_b   = (const float*)d_in[4];
    const float* gc1_w  = (const float*)d_in[5];
    const float* gc1_b  = (const float*)d_in[6];
    const float* gc2_w  = (const float*)d_in[7];
    const float* gc2_b  = (const float*)d_in[8];
    const float* fc1_w  = (const float*)d_in[9];
    const float* fc1_b  = (const float*)d_in[10];
    const float* fc2_w  = (const float*)d_in[11];
    const float* fc2_b  = (const float*)d_in[12];
    const float* cls_w  = (const float*)d_in[13];
    const float* cls_b  = (const float*)d_in[14];
    float* o = (float*)d_out;
    hipLaunchKernelGGL(gnn_mfma, dim3(NBATCH / BPB), dim3(TPB), 0, stream,
        x, adj, midx, gc_w, gc_b, gc1_w, gc1_b, gc2_w, gc2_b,
        fc1_w, fc1_b, fc2_w, fc2_b, cls_w, cls_b, o);
}